// Round 15
// baseline (462.062 us; speedup 1.0000x reference)
//
#include <hip/hip_runtime.h>
#include <cstddef>
#include <cstdint>

// ---------------------------------------------------------------------------
// MultiheadSelfAttention: x->QKV proj -> per-head RMSNorm(q,k) -> full attn
// -> out proj.  B=4, T=2048, D=2048, H=16, Hd=128.  bf16 MFMA, fp32 accum.
// R15: GEMM 8-phase -> 4 super-phase (merge quadrant pairs): halves barrier
//  count (the ~420cyc/phase sync tax) while keeping the read||stage||MFMA
//  interleave, region-death staging order, and counted-vmcnt ledger
//  identical.  Epilogues (R14 fused norm/V^T) and k_attn (R13) unchanged.
// ---------------------------------------------------------------------------

typedef __attribute__((ext_vector_type(8))) short sh8;     // 8 bf16 (4 VGPR)
typedef __attribute__((ext_vector_type(4))) float fx4;     // MFMA acc
typedef __attribute__((ext_vector_type(4))) unsigned short us4;
typedef __attribute__((ext_vector_type(4))) float f4;
typedef __attribute__((ext_vector_type(2))) unsigned uix2;
typedef unsigned short u16;

#define DEVI __device__ __forceinline__

DEVI u16 f2bf(float f) {  // round-to-nearest-even f32 -> bf16 (manual RNE)
  union { float f; unsigned u; } v; v.f = f;
  return (u16)((v.u + 0x7FFFu + ((v.u >> 16) & 1u)) >> 16);
}
DEVI float bf2f(u16 h) {
  union { unsigned u; float f; } v; v.u = ((unsigned)h) << 16;
  return v.f;
}
DEVI void gload16(const void* g, void* l) {  // async global->LDS, 16B/lane
  __builtin_amdgcn_global_load_lds((const __attribute__((address_space(1))) void*)g,
                                   (__attribute__((address_space(3))) void*)l, 16, 0, 0);
}

// ------------------------------- converts ----------------------------------
__global__ __launch_bounds__(256) void k_cvt(const float* __restrict__ in,
                                             u16* __restrict__ out, int n4) {
  int i = blockIdx.x * 256 + threadIdx.x;
  if (i >= n4) return;
  f4 v = ((const f4*)in)[i];
  us4 o;
  o[0] = f2bf(v[0]); o[1] = f2bf(v[1]); o[2] = f2bf(v[2]); o[3] = f2bf(v[3]);
  ((us4*)out)[i] = o;
}

__global__ __launch_bounds__(256) void k_cvt_w(const float* __restrict__ w0, const float* __restrict__ w1,
                                               const float* __restrict__ w2, const float* __restrict__ w3,
                                               u16* __restrict__ o0, u16* __restrict__ o1,
                                               u16* __restrict__ o2, u16* __restrict__ o3) {
  const int which = blockIdx.y;
  const float* in = which == 0 ? w0 : which == 1 ? w1 : which == 2 ? w2 : w3;
  u16* out = which == 0 ? o0 : which == 1 ? o1 : which == 2 ? o2 : o3;
  int i = blockIdx.x * 256 + threadIdx.x;
  f4 v = ((const f4*)in)[i];
  us4 o;
  o[0] = f2bf(v[0]); o[1] = f2bf(v[1]); o[2] = f2bf(v[2]); o[3] = f2bf(v[3]);
  ((us4*)out)[i] = o;
}

// =================== 256x256 BK=64 4-super-phase GEMM core ==================
DEVI void stRA(const u16* __restrict__ Ag, int m0, u16* L, int q, int kt, int tid) {
  const int rl = tid >> 3, cc = tid & 7;
#pragma unroll
  for (int j = 0; j < 2; ++j) {
    const int row = j * 128 + q * 64 + rl;
    const int g = cc ^ (row & 7);
    gload16(Ag + (size_t)(m0 + row) * 2048 + kt * 64 + g * 8,
            (char*)L + ((size_t)row * 8 + cc) * 16);
  }
}
DEVI void stRB(const u16* __restrict__ Bg, int n0, u16* L, int q, int kt, int tid) {
  const int rl = tid >> 3, cc = tid & 7;
#pragma unroll
  for (int j = 0; j < 2; ++j) {
    const int row = (j * 2 + (rl >> 5)) * 64 + q * 32 + (rl & 31);
    const int g = cc ^ (row & 7);
    gload16(Bg + (size_t)(n0 + row) * 2048 + kt * 64 + g * 8,
            (char*)L + ((size_t)row * 8 + cc) * 16);
  }
}

DEVI void rdA4(sh8 (&af)[4][2], const u16* L, int mi0, int ln, int hi) {
#pragma unroll
  for (int m = 0; m < 4; ++m)
#pragma unroll
    for (int kk = 0; kk < 2; ++kk)
      af[m][kk] = *(const sh8*)&L[(size_t)((mi0 + m) * 16 + ln) * 64 +
                                  (((kk * 4 + hi) ^ (ln & 7)) * 8)];
}
DEVI void rdB2(sh8 (&bf)[2][2], const u16* L, int row0, int ln, int hi) {
#pragma unroll
  for (int n = 0; n < 2; ++n)
#pragma unroll
    for (int kk = 0; kk < 2; ++kk)
      bf[n][kk] = *(const sh8*)&L[(size_t)(row0 + n * 16 + ln) * 64 +
                                  (((kk * 4 + hi) ^ (ln & 7)) * 8)];
}

#define MFMA_BF16 __builtin_amdgcn_mfma_f32_16x16x32_bf16
#define MMQ(MB, NB, AF, BF)                                                  \
  _Pragma("unroll") for (int kk = 0; kk < 2; ++kk)                           \
  _Pragma("unroll") for (int m2 = 0; m2 < 4; ++m2)                           \
  _Pragma("unroll") for (int n2 = 0; n2 < 2; ++n2)                           \
    acc[MB + m2][NB + n2] =                                                  \
        MFMA_BF16(AF[m2][kk], BF[n2][kk], acc[MB + m2][NB + n2], 0, 0, 0);

#define PH_OPEN()                                              \
  __builtin_amdgcn_s_barrier();                                \
  asm volatile("s_waitcnt lgkmcnt(0)" ::: "memory");           \
  __builtin_amdgcn_sched_barrier(0);                           \
  __builtin_amdgcn_s_setprio(1)
#define PH_CLOSE()                                             \
  __builtin_amdgcn_s_setprio(0);                               \
  __builtin_amdgcn_s_barrier()

DEVI void g256_loop(const u16* __restrict__ Ag, const u16* __restrict__ Bg,
                    int m0, int n0,
                    u16 (&LA)[2][16384], u16 (&LB)[2][16384],
                    fx4 (&acc)[8][4]) {
  constexpr int NI = 16;
  const int tid = threadIdx.x;
  const int lane = tid & 63, ln = lane & 15, hi = lane >> 4;
  const int wid = tid >> 6, wr = wid >> 2, wc = wid & 3;
  const int hB = wc >> 1, rBb = (wc & 1) * 64;
  const u16* A0 = &LA[0][(size_t)wr * 128 * 64];
  const u16* A1 = &LA[1][(size_t)wr * 128 * 64];
  const int rB0 = hB * 128 + rBb;

  // prologue: K-tile 0 fully + RA0/RB0 of K-tile 1
  stRA(Ag, m0, &LA[0][0], 0, 0, tid);
  stRB(Bg, n0, &LB[0][0], 0, 0, tid);
  stRA(Ag, m0, &LA[0][0], 1, 0, tid);
  stRB(Bg, n0, &LB[0][0], 1, 0, tid);
  stRA(Ag, m0, &LA[1][0], 0, 1, tid);
  stRB(Bg, n0, &LB[1][0], 0, 1, tid);
  asm volatile("s_waitcnt vmcnt(4)" ::: "memory");  // K-tile 0 landed
  __builtin_amdgcn_s_barrier();

  sh8 af[4][2], bflo[2][2], bfhi[2][2];

  for (int i = 0; i < NI; ++i) {
    const int ta = 2 * i, tb = 2 * i + 1;
    const bool stg = (i + 1 < NI);

    // ---- pair 1: quadrants (0,nlo)+(0,nhi) of ta; stage RA1(tb), RB1(tb) --
    rdA4(af, A0, 0, ln, hi);
    rdB2(bflo, &LB[0][0], rB0, ln, hi);
    rdB2(bfhi, &LB[0][0], rB0 + 32, ln, hi);
    stRA(Ag, m0, &LA[1][0], 1, tb, tid);
    stRB(Bg, n0, &LB[1][0], 1, tb, tid);
    PH_OPEN();
    MMQ(0, 0, af, bflo);
    MMQ(0, 2, af, bfhi);
    PH_CLOSE();

    // ---- pair 2: (4,nlo)+(4,nhi) of ta; stage RA0(ta+2), RB0(ta+2);
    //      vmcnt(4) drains K-tile tb's 4 regions ----
    rdA4(af, A0, 4, ln, hi);
    if (stg) { stRA(Ag, m0, &LA[0][0], 0, ta + 2, tid);
               stRB(Bg, n0, &LB[0][0], 0, ta + 2, tid); }
    PH_OPEN();
    MMQ(4, 0, af, bflo);
    MMQ(4, 2, af, bfhi);
    __builtin_amdgcn_s_setprio(0);
    if (i + 1 < NI) asm volatile("s_waitcnt vmcnt(4)" ::: "memory");
    else            asm volatile("s_waitcnt vmcnt(0)" ::: "memory");
    __builtin_amdgcn_s_barrier();

    // ---- pair 3: (0,nlo)+(0,nhi) of tb; stage RB1(ta+2), RA1(ta+2) --------
    rdA4(af, A1, 0, ln, hi);
    rdB2(bflo, &LB[1][0], rB0, ln, hi);
    rdB2(bfhi, &LB[1][0], rB0 + 32, ln, hi);
    if (stg) { stRB(Bg, n0, &LB[0][0], 1, ta + 2, tid);
               stRA(Ag, m0, &LA[0][0], 1, ta + 2, tid); }
    PH_OPEN();
    MMQ(0, 0, af, bflo);
    MMQ(0, 2, af, bfhi);
    PH_CLOSE();

    // ---- pair 4: (4,nlo)+(4,nhi) of tb; stage RA0(tb+2), RB0(tb+2);
    //      vmcnt(4) drains K-tile ta+2's 4 regions ----
    rdA4(af, A1, 4, ln, hi);
    if (stg) { stRA(Ag, m0, &LA[1][0], 0, tb + 2, tid);
               stRB(Bg, n0, &LB[1][0], 0, tb + 2, tid); }
    PH_OPEN();
    MMQ(4, 0, af, bflo);
    MMQ(4, 2, af, bfhi);
    __builtin_amdgcn_s_setprio(0);
    asm volatile("s_waitcnt vmcnt(4)" ::: "memory");
    __builtin_amdgcn_s_barrier();
  }
}

// QKV projection with fused epilogue:
//  z=0: +bias, per-head RMSNorm * qnw * log2e/sqrt(128) -> Q [B,H,T,Hd]
//  z=1: +bias, per-head RMSNorm * knw                   -> K [B,H,T,Hd]
//  z=2: +bias                                           -> V^T [B,H,Hd,T]
__global__ __launch_bounds__(512, 2) void k_gemm_qkv(
    const u16* __restrict__ A,
    const u16* __restrict__ W0, const u16* __restrict__ W1, const u16* __restrict__ W2,
    const float* __restrict__ b0, const float* __restrict__ b1, const float* __restrict__ b2,
    const float* __restrict__ qn, const float* __restrict__ kn,
    u16* __restrict__ O0, u16* __restrict__ O1, u16* __restrict__ O2) {
  __shared__ __align__(16) u16 LA[2][16384];
  __shared__ __align__(16) u16 LB[2][16384];
  int f = blockIdx.x + (blockIdx.y << 3) + (blockIdx.z << 8);
  f = (f & 7) * 96 + (f >> 3);
  const int z = f >> 8, rem = f & 255;
  const int m0 = (rem >> 3) * 256, n0 = (rem & 7) * 256;
  const u16* Bw = z == 0 ? W0 : z == 1 ? W1 : W2;
  const float* bias = z == 0 ? b0 : z == 1 ? b1 : b2;
  u16* Cout = z == 0 ? O0 : z == 1 ? O1 : O2;

  fx4 acc[8][4] = {};
  g256_loop(A, Bw, m0, n0, LA, LB, acc);

  const int tid = threadIdx.x;
  const int lane = tid & 63, ln = lane & 15, hi = lane >> 4;
  const int wid = tid >> 6, wr = wid >> 2, wc = wid & 3;

  // bias in place
#pragma unroll
  for (int nj = 0; nj < 4; ++nj) {
    const float bv = bias[n0 + wc * 64 + nj * 16 + ln];
#pragma unroll
    for (int mi = 0; mi < 8; ++mi)
#pragma unroll
      for (int j = 0; j < 4; ++j) acc[mi][nj][j] += bv;
  }

  if (z < 2) {
    // ---- fused per-head RMSNorm ----
    float ss[8][4];
#pragma unroll
    for (int mi = 0; mi < 8; ++mi)
#pragma unroll
      for (int j = 0; j < 4; ++j) {
        float s = 0.0f;
#pragma unroll
        for (int nj = 0; nj < 4; ++nj) s += acc[mi][nj][j] * acc[mi][nj][j];
#pragma unroll
        for (int m = 1; m < 16; m <<= 1) s += __shfl_xor(s, m);  // 64-col sum
        ss[mi][j] = s;
      }
    float* sums = (float*)&LA[0][0];  // [8 waves][128 rows] = 4 KB (LDS dead)
    __syncthreads();
    if (ln == 0) {
#pragma unroll
      for (int mi = 0; mi < 8; ++mi)
#pragma unroll
        for (int j = 0; j < 4; ++j)
          sums[(wr * 4 + wc) * 128 + mi * 16 + hi * 4 + j] = ss[mi][j];
    }
    __syncthreads();
    const float zscale = z == 0 ? 0.12751745047f : 1.0f;  // log2e/sqrt(128)
    const float* wnorm = z == 0 ? qn : kn;
#pragma unroll
    for (int mi = 0; mi < 8; ++mi)
#pragma unroll
      for (int j = 0; j < 4; ++j) {
        const float tot = ss[mi][j] +
            sums[(wr * 4 + (wc ^ 1)) * 128 + mi * 16 + hi * 4 + j];
        ss[mi][j] = rsqrtf(tot * (1.0f / 128.0f) + 1.1920928955078125e-07f) * zscale;
      }
#pragma unroll
    for (int mi = 0; mi < 8; ++mi) {
#pragma unroll
      for (int nj = 0; nj < 4; ++nj) {
        const int col = n0 + wc * 64 + nj * 16 + ln;
        const int h = col >> 7, d = col & 127;
        const float wv = wnorm[d];
#pragma unroll
        for (int j = 0; j < 4; ++j) {
          const int row = m0 + wr * 128 + mi * 16 + hi * 4 + j;
          const int b = row >> 11, t = row & 2047;
          Cout[((((size_t)b * 16 + h) * 2048) + t) * 128 + d] =
              f2bf(acc[mi][nj][j] * ss[mi][j] * wv);
        }
      }
    }
  } else {
    // ---- V: write V^T directly [B,H,Hd,T]; 4 consecutive t's = 8B store ---
#pragma unroll
    for (int mi = 0; mi < 8; ++mi) {
#pragma unroll
      for (int nj = 0; nj < 4; ++nj) {
        const int col = n0 + wc * 64 + nj * 16 + ln;
        const int h = col >> 7, d = col & 127;
        const int row0 = m0 + wr * 128 + mi * 16 + hi * 4;
        const int b = row0 >> 11, t = row0 & 2047;
        us4 v;
#pragma unroll
        for (int j = 0; j < 4; ++j) v[j] = f2bf(acc[mi][nj][j]);
        *(us4*)&Cout[((((size_t)b * 16 + h) * 128) + d) * 2048 + t] = v;
      }
    }
  }
}

// Output projection: fp32 row-major + bias.
__global__ __launch_bounds__(512, 2) void k_gemm_out(const u16* __restrict__ A,
                                                     const u16* __restrict__ Bw,
                                                     const float* __restrict__ bias,
                                                     float* __restrict__ C) {
  __shared__ __align__(16) u16 LA[2][16384];
  __shared__ __align__(16) u16 LB[2][16384];
  int f = blockIdx.x + (blockIdx.y << 3);
  f = (f & 7) * 32 + (f >> 3);
  const int m0 = (f >> 3) * 256, n0 = (f & 7) * 256;

  fx4 acc[8][4] = {};
  g256_loop(A, Bw, m0, n0, LA, LB, acc);

  const int tid = threadIdx.x;
  const int lane = tid & 63, ln = lane & 15, hi = lane >> 4;
  const int wid = tid >> 6, wr = wid >> 2, wc = wid & 3;
#pragma unroll
  for (int mi = 0; mi < 8; ++mi) {
#pragma unroll
    for (int nj = 0; nj < 4; ++nj) {
      const int col = n0 + wc * 64 + nj * 16 + ln;
      const float bv = bias[col];
#pragma unroll
      for (int j = 0; j < 4; ++j) {
        const int row = m0 + wr * 128 + mi * 16 + hi * 4 + j;
        C[(size_t)row * 2048 + col] = acc[mi][nj][j] + bv;
      }
    }
  }
}

// --------------------------- Flash attention -------------------------------
// 4 waves x 32 q-rows, KV tile 64.  Swapped QK^T (S^T = K.Q^T), packed 8B
// P-writes, fixed-max base-2 softmax (log2e folded into Q), 2-phase dbuf.
__global__ __launch_bounds__(256, 2) void k_attn(const u16* __restrict__ Q,
                                                 const u16* __restrict__ Kt,
                                                 const u16* __restrict__ Vt,
                                                 u16* __restrict__ Aout) {
  constexpr int T = 2048, Hd = 128;
  __shared__ __align__(16) u16 Ks[2][64 * 128];
  __shared__ __align__(16) u16 Vs[2][128 * 64];
  __shared__ __align__(16) u16 Ps[4 * 32 * 64];
  const int tid = threadIdx.x;
  const int w = tid >> 6, lane = tid & 63;
  const int ln = lane & 15, hi = lane >> 4;
  const int bh = blockIdx.y;
  const int q0 = blockIdx.x * 128 + w * 32;

  const u16* Kgb = Kt + (size_t)bh * T * Hd;
  const u16* Vgb = Vt + (size_t)bh * Hd * T;
  u16* Pw = Ps + w * 2048;

  sh8 qf[2][4];
  const u16* Qb = Q + ((size_t)bh * T + q0) * Hd;
#pragma unroll
  for (int mi = 0; mi < 2; ++mi)
#pragma unroll
    for (int ks = 0; ks < 4; ++ks)
      qf[mi][ks] = *(const sh8*)(Qb + (size_t)(mi * 16 + ln) * Hd + ks * 32 + hi * 8);

  fx4 o[2][8] = {};
  float lsum[2] = {0.0f, 0.0f};

  auto stage = [&](int buf, int t0) {
#pragma unroll
    for (int i = 0; i < 4; ++i) {
      const int c = i * 256 + tid;
      const int r = c >> 4, cc = (c & 15) ^ (r & 7);
      gload16(Kgb + (size_t)(t0 + r) * Hd + cc * 8, (char*)&Ks[buf][0] + c * 16);
    }
#pragma unroll
    for (int i = 0; i < 4; ++i) {
      const int c = i * 256 + tid;
      const int r = c >> 3, cc = (c & 7) ^ (r & 7);
      gload16(Vgb + (size_t)r * T + t0 + cc * 8, (char*)&Vs[buf][0] + c * 16);
    }
  };

  stage(0, 0);
  __syncthreads();
  int cur = 0;

  for (int t0 = 0; t0 < T; t0 += 64) {
    if (t0 + 64 < T) stage(cur ^ 1, t0 + 64);

#pragma unroll
    for (int ni = 0; ni < 4; ++ni) {
      sh8 kf[4];
#pragma unroll
      for (int ks = 0; ks < 4; ++ks)
        kf[ks] = *(const sh8*)&Ks[cur][(((ni * 16 + ln) * 128) + ks * 32 + hi * 8) ^ ((ln & 7) << 3)];
      fx4 st[2] = {};
#pragma unroll
      for (int mi = 0; mi < 2; ++mi)
#pragma unroll
        for (int ks = 0; ks < 4; ++ks)
          st[mi] = MFMA_BF16(kf[ks], qf[mi][ks], st[mi], 0, 0, 0);
#pragma unroll
      for (int mi = 0; mi < 2; ++mi) {
        const float p0 = __builtin_amdgcn_exp2f(st[mi][0] - 17.31234049066756f);
        const float p1 = __builtin_amdgcn_exp2f(st[mi][1] - 17.31234049066756f);
        const float p2 = __builtin_amdgcn_exp2f(st[mi][2] - 17.31234049066756f);
        const float p3 = __builtin_amdgcn_exp2f(st[mi][3] - 17.31234049066756f);
        lsum[mi] += (p0 + p1) + (p2 + p3);
        const unsigned lo = (unsigned)f2bf(p0) | ((unsigned)f2bf(p1) << 16);
        const unsigned hw = (unsigned)f2bf(p2) | ((unsigned)f2bf(p3) << 16);
        const int idx = (((mi * 16 + ln) * 64) + ni * 16 + hi * 4) ^ ((ln & 7) << 3);
        *(uix2*)&Pw[idx] = (uix2){lo, hw};
      }
    }

#pragma unroll
    for (int ks = 0; ks < 2; ++ks) {
      sh8 pf[2];
#pragma unroll
      for (int mi = 0; mi < 2; ++mi)
        pf[mi] = *(const sh8*)&Pw[(((mi * 16 + ln) * 64) + ks * 32 + hi * 8) ^ ((ln & 7) << 3)];
#pragma unroll
      for (int di = 0; di < 8; ++di) {
        const sh8 vf = *(const sh8*)&Vs[cur][(((di * 16 + ln) * 64) + ks * 32 + hi * 8) ^ ((ln & 7) << 3)];
#pragma unroll
        for (int mi = 0; mi < 2; ++mi)
          o[mi][di] = MFMA_BF16(pf[mi], vf, o[mi][di], 0, 0, 0);
      }
    }

    __syncthreads();
    cur ^= 1;
  }

#pragma unroll
  for (int mi = 0; mi < 2; ++mi) {
    lsum[mi] += __shfl_xor(lsum[mi], 16);
    lsum[mi] += __shfl_xor(lsum[mi], 32);
  }

  const int b = bh >> 4, h = bh & 15;
  u16* Ob = Aout + ((size_t)b * T + q0) * 2048 + h * 128;
#pragma unroll
  for (int mi = 0; mi < 2; ++mi) {
    fx4 rv;
#pragma unroll
    for (int j = 0; j < 4; ++j)
      rv[j] = 1.0f / __shfl(lsum[mi], 20 * (lane >> 4) + j);
#pragma unroll
    for (int di = 0; di < 8; ++di) {
      fx4 val = o[mi][di] * rv;
#pragma unroll
      for (int j = 0; j < 4; ++j)
        Ob[(size_t)(mi * 16 + hi * 4 + j) * 2048 + di * 16 + ln] = f2bf(val[j]);
    }
  }
}

// ---------------------------------------------------------------------------
extern "C" void kernel_launch(void* const* d_in, const int* in_sizes, int n_in,
                              void* d_out, int out_size, void* d_ws, size_t ws_size,
                              hipStream_t stream) {
  const float* x   = (const float*)d_in[0];
  const float* Wq  = (const float*)d_in[1];
  const float* bq  = (const float*)d_in[2];
  const float* Wk  = (const float*)d_in[3];
  const float* bk  = (const float*)d_in[4];
  const float* Wv  = (const float*)d_in[5];
  const float* bv  = (const float*)d_in[6];
  const float* qnw = (const float*)d_in[7];
  const float* knw = (const float*)d_in[8];
  const float* Wo  = (const float*)d_in[9];
  const float* bo  = (const float*)d_in[10];
  float* out = (float*)d_out;

  const size_t SZ_X = 33554432;  // 8192*2048 bf16
  const size_t SZ_W = 8388608;   // 2048*2048 bf16
  char* ws = (char*)d_ws;
  u16* xb  = (u16*)(ws);
  u16* Wqb = (u16*)(ws + SZ_X);
  u16* Wkb = (u16*)(ws + SZ_X + SZ_W);
  u16* Wvb = (u16*)(ws + SZ_X + 2 * SZ_W);
  u16* Wob = (u16*)(ws + SZ_X + 3 * SZ_W);
  u16* Qb  = (u16*)(ws + SZ_X + 4 * SZ_W);
  u16* Kb  = (u16*)(ws + 2 * SZ_X + 4 * SZ_W);
  u16* Vb  = (u16*)(ws + 3 * SZ_X + 4 * SZ_W);   // attn-out scratch
  u16* Vtb = (u16*)(ws + 4 * SZ_X + 4 * SZ_W);
  u16* AOb = Vb;

  k_cvt<<<16384, 256, 0, stream>>>(x, xb, 4194304);
  k_cvt_w<<<dim3(4096, 4), 256, 0, stream>>>(Wq, Wk, Wv, Wo, Wqb, Wkb, Wvb, Wob);
  k_gemm_qkv<<<dim3(8, 32, 3), 512, 0, stream>>>(xb, Wqb, Wkb, Wvb, bq, bk, bv,
                                                 qnw, knw, Qb, Kb, Vtb);
  k_attn<<<dim3(16, 64), 256, 0, stream>>>(Qb, Kb, Vtb, AOb);
  k_gemm_out<<<dim3(8, 32), 512, 0, stream>>>(AOb, Wob, bo, out);
}

// Round 16
// 456.356 us; speedup vs baseline: 1.0125x; 1.0125x over previous
//
#include <hip/hip_runtime.h>
#include <cstddef>
#include <cstdint>

// ---------------------------------------------------------------------------
// MultiheadSelfAttention: x->QKV proj -> per-head RMSNorm(q,k) -> full attn
// -> out proj.  B=4, T=2048, D=2048, H=16, Hd=128.  bf16 MFMA, fp32 accum.
// R16: revert GEMM core to R14's 8-phase schedule (R15's 4-super-phase merge
//  regressed: fewer/longer compute windows hurt cross-wave overlap, m196).
//  Plus: k_cvt + k_cvt_w merged into one flat launch (5 -> 4 launches).
//  Fused epilogues (R14) and k_attn (R13) unchanged.
// ---------------------------------------------------------------------------

typedef __attribute__((ext_vector_type(8))) short sh8;     // 8 bf16 (4 VGPR)
typedef __attribute__((ext_vector_type(4))) float fx4;     // MFMA acc
typedef __attribute__((ext_vector_type(4))) unsigned short us4;
typedef __attribute__((ext_vector_type(4))) float f4;
typedef __attribute__((ext_vector_type(2))) unsigned uix2;
typedef unsigned short u16;

#define DEVI __device__ __forceinline__

DEVI u16 f2bf(float f) {  // round-to-nearest-even f32 -> bf16 (manual RNE)
  union { float f; unsigned u; } v; v.f = f;
  return (u16)((v.u + 0x7FFFu + ((v.u >> 16) & 1u)) >> 16);
}
DEVI float bf2f(u16 h) {
  union { unsigned u; float f; } v; v.u = ((unsigned)h) << 16;
  return v.f;
}
DEVI void gload16(const void* g, void* l) {  // async global->LDS, 16B/lane
  __builtin_amdgcn_global_load_lds((const __attribute__((address_space(1))) void*)g,
                                   (__attribute__((address_space(3))) void*)l, 16, 0, 0);
}

// ------------------------------- converts ----------------------------------
// One launch converts x (4.19M f4) + Wq/Wk/Wv/Wo (1.05M f4 each) to bf16.
__global__ __launch_bounds__(256) void k_cvt_all(
    const float* __restrict__ x,  const float* __restrict__ w0,
    const float* __restrict__ w1, const float* __restrict__ w2,
    const float* __restrict__ w3,
    u16* __restrict__ ox, u16* __restrict__ o0, u16* __restrict__ o1,
    u16* __restrict__ o2, u16* __restrict__ o3) {
  int blk = blockIdx.x;
  const float* in; u16* out; int i;
  if (blk < 16384) { in = x; out = ox; i = blk * 256 + threadIdx.x; }
  else {
    blk -= 16384;
    const int which = blk >> 12;       // 4096 blocks per weight
    in  = which == 0 ? w0 : which == 1 ? w1 : which == 2 ? w2 : w3;
    out = which == 0 ? o0 : which == 1 ? o1 : which == 2 ? o2 : o3;
    i = (blk & 4095) * 256 + threadIdx.x;
  }
  f4 v = ((const f4*)in)[i];
  us4 o;
  o[0] = f2bf(v[0]); o[1] = f2bf(v[1]); o[2] = f2bf(v[2]); o[3] = f2bf(v[3]);
  ((us4*)out)[i] = o;
}

// =================== 256x256 BK=64 8-phase GEMM core ========================
DEVI void stRA(const u16* __restrict__ Ag, int m0, u16* L, int q, int kt, int tid) {
  const int rl = tid >> 3, cc = tid & 7;
#pragma unroll
  for (int j = 0; j < 2; ++j) {
    const int row = j * 128 + q * 64 + rl;
    const int g = cc ^ (row & 7);
    gload16(Ag + (size_t)(m0 + row) * 2048 + kt * 64 + g * 8,
            (char*)L + ((size_t)row * 8 + cc) * 16);
  }
}
DEVI void stRB(const u16* __restrict__ Bg, int n0, u16* L, int q, int kt, int tid) {
  const int rl = tid >> 3, cc = tid & 7;
#pragma unroll
  for (int j = 0; j < 2; ++j) {
    const int row = (j * 2 + (rl >> 5)) * 64 + q * 32 + (rl & 31);
    const int g = cc ^ (row & 7);
    gload16(Bg + (size_t)(n0 + row) * 2048 + kt * 64 + g * 8,
            (char*)L + ((size_t)row * 8 + cc) * 16);
  }
}

DEVI void rdA4(sh8 (&af)[4][2], const u16* L, int mi0, int ln, int hi) {
#pragma unroll
  for (int m = 0; m < 4; ++m)
#pragma unroll
    for (int kk = 0; kk < 2; ++kk)
      af[m][kk] = *(const sh8*)&L[(size_t)((mi0 + m) * 16 + ln) * 64 +
                                  (((kk * 4 + hi) ^ (ln & 7)) * 8)];
}
DEVI void rdB2(sh8 (&bf)[2][2], const u16* L, int row0, int ln, int hi) {
#pragma unroll
  for (int n = 0; n < 2; ++n)
#pragma unroll
    for (int kk = 0; kk < 2; ++kk)
      bf[n][kk] = *(const sh8*)&L[(size_t)(row0 + n * 16 + ln) * 64 +
                                  (((kk * 4 + hi) ^ (ln & 7)) * 8)];
}

#define MFMA_BF16 __builtin_amdgcn_mfma_f32_16x16x32_bf16
#define MMQ(MB, NB, AF, BF)                                                  \
  _Pragma("unroll") for (int kk = 0; kk < 2; ++kk)                           \
  _Pragma("unroll") for (int m2 = 0; m2 < 4; ++m2)                           \
  _Pragma("unroll") for (int n2 = 0; n2 < 2; ++n2)                           \
    acc[MB + m2][NB + n2] =                                                  \
        MFMA_BF16(AF[m2][kk], BF[n2][kk], acc[MB + m2][NB + n2], 0, 0, 0);

#define PH_OPEN()                                              \
  __builtin_amdgcn_s_barrier();                                \
  asm volatile("s_waitcnt lgkmcnt(0)" ::: "memory");           \
  __builtin_amdgcn_sched_barrier(0);                           \
  __builtin_amdgcn_s_setprio(1)
#define PH_CLOSE()                                             \
  __builtin_amdgcn_s_setprio(0);                               \
  __builtin_amdgcn_s_barrier()

DEVI void g256_loop(const u16* __restrict__ Ag, const u16* __restrict__ Bg,
                    int m0, int n0,
                    u16 (&LA)[2][16384], u16 (&LB)[2][16384],
                    fx4 (&acc)[8][4]) {
  constexpr int NI = 16;
  const int tid = threadIdx.x;
  const int lane = tid & 63, ln = lane & 15, hi = lane >> 4;
  const int wid = tid >> 6, wr = wid >> 2, wc = wid & 3;
  const int hB = wc >> 1, rBb = (wc & 1) * 64;
  const u16* A0 = &LA[0][(size_t)wr * 128 * 64];
  const u16* A1 = &LA[1][(size_t)wr * 128 * 64];
  const int rB0 = hB * 128 + rBb;

  stRA(Ag, m0, &LA[0][0], 0, 0, tid);
  stRB(Bg, n0, &LB[0][0], 0, 0, tid);
  stRA(Ag, m0, &LA[0][0], 1, 0, tid);
  stRB(Bg, n0, &LB[0][0], 1, 0, tid);
  stRA(Ag, m0, &LA[1][0], 0, 1, tid);
  stRB(Bg, n0, &LB[1][0], 0, 1, tid);
  asm volatile("s_waitcnt vmcnt(4)" ::: "memory");
  __builtin_amdgcn_s_barrier();

  sh8 af[4][2], bflo[2][2], bfhi[2][2];

  for (int i = 0; i < NI; ++i) {
    const int ta = 2 * i, tb = 2 * i + 1;
    const bool stg = (i + 1 < NI);

    rdA4(af, A0, 0, ln, hi);
    rdB2(bflo, &LB[0][0], rB0, ln, hi);
    stRA(Ag, m0, &LA[1][0], 1, tb, tid);
    PH_OPEN(); MMQ(0, 0, af, bflo); PH_CLOSE();

    rdB2(bfhi, &LB[0][0], rB0 + 32, ln, hi);
    stRB(Bg, n0, &LB[1][0], 1, tb, tid);
    PH_OPEN(); MMQ(0, 2, af, bfhi); PH_CLOSE();

    rdA4(af, A0, 4, ln, hi);
    if (stg) stRA(Ag, m0, &LA[0][0], 0, ta + 2, tid);
    PH_OPEN(); MMQ(4, 0, af, bflo); PH_CLOSE();

    if (stg) stRB(Bg, n0, &LB[0][0], 0, ta + 2, tid);
    PH_OPEN(); MMQ(4, 2, af, bfhi);
    __builtin_amdgcn_s_setprio(0);
    if (i + 1 < NI) asm volatile("s_waitcnt vmcnt(4)" ::: "memory");
    else            asm volatile("s_waitcnt vmcnt(0)" ::: "memory");
    __builtin_amdgcn_s_barrier();

    rdA4(af, A1, 0, ln, hi);
    rdB2(bflo, &LB[1][0], rB0, ln, hi);
    if (stg) stRB(Bg, n0, &LB[0][0], 1, ta + 2, tid);
    PH_OPEN(); MMQ(0, 0, af, bflo); PH_CLOSE();

    rdB2(bfhi, &LB[1][0], rB0 + 32, ln, hi);
    if (stg) stRA(Ag, m0, &LA[0][0], 1, ta + 2, tid);
    PH_OPEN(); MMQ(0, 2, af, bfhi); PH_CLOSE();

    rdA4(af, A1, 4, ln, hi);
    if (stg) stRA(Ag, m0, &LA[1][0], 0, tb + 2, tid);
    PH_OPEN(); MMQ(4, 0, af, bflo); PH_CLOSE();

    if (stg) stRB(Bg, n0, &LB[1][0], 0, tb + 2, tid);
    PH_OPEN(); MMQ(4, 2, af, bfhi);
    __builtin_amdgcn_s_setprio(0);
    asm volatile("s_waitcnt vmcnt(4)" ::: "memory");
    __builtin_amdgcn_s_barrier();
  }
}

// QKV projection with fused epilogue:
//  z=0: +bias, per-head RMSNorm * qnw * log2e/sqrt(128) -> Q [B,H,T,Hd]
//  z=1: +bias, per-head RMSNorm * knw                   -> K [B,H,T,Hd]
//  z=2: +bias                                           -> V^T [B,H,Hd,T]
__global__ __launch_bounds__(512, 2) void k_gemm_qkv(
    const u16* __restrict__ A,
    const u16* __restrict__ W0, const u16* __restrict__ W1, const u16* __restrict__ W2,
    const float* __restrict__ b0, const float* __restrict__ b1, const float* __restrict__ b2,
    const float* __restrict__ qn, const float* __restrict__ kn,
    u16* __restrict__ O0, u16* __restrict__ O1, u16* __restrict__ O2) {
  __shared__ __align__(16) u16 LA[2][16384];
  __shared__ __align__(16) u16 LB[2][16384];
  int f = blockIdx.x + (blockIdx.y << 3) + (blockIdx.z << 8);
  f = (f & 7) * 96 + (f >> 3);
  const int z = f >> 8, rem = f & 255;
  const int m0 = (rem >> 3) * 256, n0 = (rem & 7) * 256;
  const u16* Bw = z == 0 ? W0 : z == 1 ? W1 : W2;
  const float* bias = z == 0 ? b0 : z == 1 ? b1 : b2;
  u16* Cout = z == 0 ? O0 : z == 1 ? O1 : O2;

  fx4 acc[8][4] = {};
  g256_loop(A, Bw, m0, n0, LA, LB, acc);

  const int tid = threadIdx.x;
  const int lane = tid & 63, ln = lane & 15, hi = lane >> 4;
  const int wid = tid >> 6, wr = wid >> 2, wc = wid & 3;

#pragma unroll
  for (int nj = 0; nj < 4; ++nj) {
    const float bv = bias[n0 + wc * 64 + nj * 16 + ln];
#pragma unroll
    for (int mi = 0; mi < 8; ++mi)
#pragma unroll
      for (int j = 0; j < 4; ++j) acc[mi][nj][j] += bv;
  }

  if (z < 2) {
    float ss[8][4];
#pragma unroll
    for (int mi = 0; mi < 8; ++mi)
#pragma unroll
      for (int j = 0; j < 4; ++j) {
        float s = 0.0f;
#pragma unroll
        for (int nj = 0; nj < 4; ++nj) s += acc[mi][nj][j] * acc[mi][nj][j];
#pragma unroll
        for (int m = 1; m < 16; m <<= 1) s += __shfl_xor(s, m);
        ss[mi][j] = s;
      }
    float* sums = (float*)&LA[0][0];  // 4 KB scratch, LDS dead post-loop
    __syncthreads();
    if (ln == 0) {
#pragma unroll
      for (int mi = 0; mi < 8; ++mi)
#pragma unroll
        for (int j = 0; j < 4; ++j)
          sums[(wr * 4 + wc) * 128 + mi * 16 + hi * 4 + j] = ss[mi][j];
    }
    __syncthreads();
    const float zscale = z == 0 ? 0.12751745047f : 1.0f;  // log2e/sqrt(128)
    const float* wnorm = z == 0 ? qn : kn;
#pragma unroll
    for (int mi = 0; mi < 8; ++mi)
#pragma unroll
      for (int j = 0; j < 4; ++j) {
        const float tot = ss[mi][j] +
            sums[(wr * 4 + (wc ^ 1)) * 128 + mi * 16 + hi * 4 + j];
        ss[mi][j] = rsqrtf(tot * (1.0f / 128.0f) + 1.1920928955078125e-07f) * zscale;
      }
#pragma unroll
    for (int mi = 0; mi < 8; ++mi) {
#pragma unroll
      for (int nj = 0; nj < 4; ++nj) {
        const int col = n0 + wc * 64 + nj * 16 + ln;
        const int h = col >> 7, d = col & 127;
        const float wv = wnorm[d];
#pragma unroll
        for (int j = 0; j < 4; ++j) {
          const int row = m0 + wr * 128 + mi * 16 + hi * 4 + j;
          const int b = row >> 11, t = row & 2047;
          Cout[((((size_t)b * 16 + h) * 2048) + t) * 128 + d] =
              f2bf(acc[mi][nj][j] * ss[mi][j] * wv);
        }
      }
    }
  } else {
#pragma unroll
    for (int mi = 0; mi < 8; ++mi) {
#pragma unroll
      for (int nj = 0; nj < 4; ++nj) {
        const int col = n0 + wc * 64 + nj * 16 + ln;
        const int h = col >> 7, d = col & 127;
        const int row0 = m0 + wr * 128 + mi * 16 + hi * 4;
        const int b = row0 >> 11, t = row0 & 2047;
        us4 v;
#pragma unroll
        for (int j = 0; j < 4; ++j) v[j] = f2bf(acc[mi][nj][j]);
        *(us4*)&Cout[((((size_t)b * 16 + h) * 128) + d) * 2048 + t] = v;
      }
    }
  }
}

// Output projection: fp32 row-major + bias.
__global__ __launch_bounds__(512, 2) void k_gemm_out(const u16* __restrict__ A,
                                                     const u16* __restrict__ Bw,
                                                     const float* __restrict__ bias,
                                                     float* __restrict__ C) {
  __shared__ __align__(16) u16 LA[2][16384];
  __shared__ __align__(16) u16 LB[2][16384];
  int f = blockIdx.x + (blockIdx.y << 3);
  f = (f & 7) * 32 + (f >> 3);
  const int m0 = (f >> 3) * 256, n0 = (f & 7) * 256;

  fx4 acc[8][4] = {};
  g256_loop(A, Bw, m0, n0, LA, LB, acc);

  const int tid = threadIdx.x;
  const int lane = tid & 63, ln = lane & 15, hi = lane >> 4;
  const int wid = tid >> 6, wr = wid >> 2, wc = wid & 3;
#pragma unroll
  for (int mi = 0; mi < 8; ++mi) {
#pragma unroll
    for (int nj = 0; nj < 4; ++nj) {
      const int col = n0 + wc * 64 + nj * 16 + ln;
      const float bv = bias[col];
#pragma unroll
      for (int j = 0; j < 4; ++j) {
        const int row = m0 + wr * 128 + mi * 16 + hi * 4 + j;
        C[(size_t)row * 2048 + col] = acc[mi][nj][j] + bv;
      }
    }
  }
}

// --------------------------- Flash attention -------------------------------
// 4 waves x 32 q-rows, KV tile 64.  Swapped QK^T (S^T = K.Q^T), packed 8B
// P-writes, fixed-max base-2 softmax (log2e folded into Q), 2-phase dbuf.
__global__ __launch_bounds__(256, 2) void k_attn(const u16* __restrict__ Q,
                                                 const u16* __restrict__ Kt,
                                                 const u16* __restrict__ Vt,
                                                 u16* __restrict__ Aout) {
  constexpr int T = 2048, Hd = 128;
  __shared__ __align__(16) u16 Ks[2][64 * 128];
  __shared__ __align__(16) u16 Vs[2][128 * 64];
  __shared__ __align__(16) u16 Ps[4 * 32 * 64];
  const int tid = threadIdx.x;
  const int w = tid >> 6, lane = tid & 63;
  const int ln = lane & 15, hi = lane >> 4;
  const int bh = blockIdx.y;
  const int q0 = blockIdx.x * 128 + w * 32;

  const u16* Kgb = Kt + (size_t)bh * T * Hd;
  const u16* Vgb = Vt + (size_t)bh * Hd * T;
  u16* Pw = Ps + w * 2048;

  sh8 qf[2][4];
  const u16* Qb = Q + ((size_t)bh * T + q0) * Hd;
#pragma unroll
  for (int mi = 0; mi < 2; ++mi)
#pragma unroll
    for (int ks = 0; ks < 4; ++ks)
      qf[mi][ks] = *(const sh8*)(Qb + (size_t)(mi * 16 + ln) * Hd + ks * 32 + hi * 8);

  fx4 o[2][8] = {};
  float lsum[2] = {0.0f, 0.0f};

  auto stage = [&](int buf, int t0) {
#pragma unroll
    for (int i = 0; i < 4; ++i) {
      const int c = i * 256 + tid;
      const int r = c >> 4, cc = (c & 15) ^ (r & 7);
      gload16(Kgb + (size_t)(t0 + r) * Hd + cc * 8, (char*)&Ks[buf][0] + c * 16);
    }
#pragma unroll
    for (int i = 0; i < 4; ++i) {
      const int c = i * 256 + tid;
      const int r = c >> 3, cc = (c & 7) ^ (r & 7);
      gload16(Vgb + (size_t)r * T + t0 + cc * 8, (char*)&Vs[buf][0] + c * 16);
    }
  };

  stage(0, 0);
  __syncthreads();
  int cur = 0;

  for (int t0 = 0; t0 < T; t0 += 64) {
    if (t0 + 64 < T) stage(cur ^ 1, t0 + 64);

#pragma unroll
    for (int ni = 0; ni < 4; ++ni) {
      sh8 kf[4];
#pragma unroll
      for (int ks = 0; ks < 4; ++ks)
        kf[ks] = *(const sh8*)&Ks[cur][(((ni * 16 + ln) * 128) + ks * 32 + hi * 8) ^ ((ln & 7) << 3)];
      fx4 st[2] = {};
#pragma unroll
      for (int mi = 0; mi < 2; ++mi)
#pragma unroll
        for (int ks = 0; ks < 4; ++ks)
          st[mi] = MFMA_BF16(kf[ks], qf[mi][ks], st[mi], 0, 0, 0);
#pragma unroll
      for (int mi = 0; mi < 2; ++mi) {
        const float p0 = __builtin_amdgcn_exp2f(st[mi][0] - 17.31234049066756f);
        const float p1 = __builtin_amdgcn_exp2f(st[mi][1] - 17.31234049066756f);
        const float p2 = __builtin_amdgcn_exp2f(st[mi][2] - 17.31234049066756f);
        const float p3 = __builtin_amdgcn_exp2f(st[mi][3] - 17.31234049066756f);
        lsum[mi] += (p0 + p1) + (p2 + p3);
        const unsigned lo = (unsigned)f2bf(p0) | ((unsigned)f2bf(p1) << 16);
        const unsigned hw = (unsigned)f2bf(p2) | ((unsigned)f2bf(p3) << 16);
        const int idx = (((mi * 16 + ln) * 64) + ni * 16 + hi * 4) ^ ((ln & 7) << 3);
        *(uix2*)&Pw[idx] = (uix2){lo, hw};
      }
    }

#pragma unroll
    for (int ks = 0; ks < 2; ++ks) {
      sh8 pf[2];
#pragma unroll
      for (int mi = 0; mi < 2; ++mi)
        pf[mi] = *(const sh8*)&Pw[(((mi * 16 + ln) * 64) + ks * 32 + hi * 8) ^ ((ln & 7) << 3)];
#pragma unroll
      for (int di = 0; di < 8; ++di) {
        const sh8 vf = *(const sh8*)&Vs[cur][(((di * 16 + ln) * 64) + ks * 32 + hi * 8) ^ ((ln & 7) << 3)];
#pragma unroll
        for (int mi = 0; mi < 2; ++mi)
          o[mi][di] = MFMA_BF16(pf[mi], vf, o[mi][di], 0, 0, 0);
      }
    }

    __syncthreads();
    cur ^= 1;
  }

#pragma unroll
  for (int mi = 0; mi < 2; ++mi) {
    lsum[mi] += __shfl_xor(lsum[mi], 16);
    lsum[mi] += __shfl_xor(lsum[mi], 32);
  }

  const int b = bh >> 4, h = bh & 15;
  u16* Ob = Aout + ((size_t)b * T + q0) * 2048 + h * 128;
#pragma unroll
  for (int mi = 0; mi < 2; ++mi) {
    fx4 rv;
#pragma unroll
    for (int j = 0; j < 4; ++j)
      rv[j] = 1.0f / __shfl(lsum[mi], 20 * (lane >> 4) + j);
#pragma unroll
    for (int di = 0; di < 8; ++di) {
      fx4 val = o[mi][di] * rv;
#pragma unroll
      for (int j = 0; j < 4; ++j)
        Ob[(size_t)(mi * 16 + hi * 4 + j) * 2048 + di * 16 + ln] = f2bf(val[j]);
    }
  }
}

// ---------------------------------------------------------------------------
extern "C" void kernel_launch(void* const* d_in, const int* in_sizes, int n_in,
                              void* d_out, int out_size, void* d_ws, size_t ws_size,
                              hipStream_t stream) {
  const float* x   = (const float*)d_in[0];
  const float* Wq  = (const float*)d_in[1];
  const float* bq  = (const float*)d_in[2];
  const float* Wk  = (const float*)d_in[3];
  const float* bk  = (const float*)d_in[4];
  const float* Wv  = (const float*)d_in[5];
  const float* bv  = (const float*)d_in[6];
  const float* qnw = (const float*)d_in[7];
  const float* knw = (const float*)d_in[8];
  const float* Wo  = (const float*)d_in[9];
  const float* bo  = (const float*)d_in[10];
  float* out = (float*)d_out;

  const size_t SZ_X = 33554432;  // 8192*2048 bf16
  const size_t SZ_W = 8388608;   // 2048*2048 bf16
  char* ws = (char*)d_ws;
  u16* xb  = (u16*)(ws);
  u16* Wqb = (u16*)(ws + SZ_X);
  u16* Wkb = (u16*)(ws + SZ_X + SZ_W);
  u16* Wvb = (u16*)(ws + SZ_X + 2 * SZ_W);
  u16* Wob = (u16*)(ws + SZ_X + 3 * SZ_W);
  u16* Qb  = (u16*)(ws + SZ_X + 4 * SZ_W);
  u16* Kb  = (u16*)(ws + 2 * SZ_X + 4 * SZ_W);
  u16* Vb  = (u16*)(ws + 3 * SZ_X + 4 * SZ_W);   // attn-out scratch
  u16* Vtb = (u16*)(ws + 4 * SZ_X + 4 * SZ_W);
  u16* AOb = Vb;

  k_cvt_all<<<32768, 256, 0, stream>>>(x, Wq, Wk, Wv, Wo, xb, Wqb, Wkb, Wvb, Wob);
  k_gemm_qkv<<<dim3(8, 32, 3), 512, 0, stream>>>(xb, Wqb, Wkb, Wvb, bq, bk, bv,
                                                 qnw, knw, Qb, Kb, Vtb);
  k_attn<<<dim3(16, 64), 256, 0, stream>>>(Qb, Kb, Vtb, AOb);
  k_gemm_out<<<dim3(8, 32), 512, 0, stream>>>(AOb, Wob, bo, out);
}

// Round 17
// 448.126 us; speedup vs baseline: 1.0311x; 1.0184x over previous
//
#include <hip/hip_runtime.h>
#include <cstddef>
#include <cstdint>

// ---------------------------------------------------------------------------
// MultiheadSelfAttention: x->QKV proj -> per-head RMSNorm(q,k) -> full attn
// -> out proj.  B=4, T=2048, D=2048, H=16, Hd=128.  bf16 MFMA, fp32 accum.
// R17: attn XCD-affinity remap (T1): all 16 q-blocks of one bh pinned to one
//  XCD (bijective over 1024 blocks) so K/V stay L2-resident -> staging
//  prefetch latency (~900cy HBM vs ~200cy L2) fully hidden by the 2-phase
//  pipeline.  Everything else identical to R16 (best: 456.4 us).
// ---------------------------------------------------------------------------

typedef __attribute__((ext_vector_type(8))) short sh8;     // 8 bf16 (4 VGPR)
typedef __attribute__((ext_vector_type(4))) float fx4;     // MFMA acc
typedef __attribute__((ext_vector_type(4))) unsigned short us4;
typedef __attribute__((ext_vector_type(4))) float f4;
typedef __attribute__((ext_vector_type(2))) unsigned uix2;
typedef unsigned short u16;

#define DEVI __device__ __forceinline__

DEVI u16 f2bf(float f) {  // round-to-nearest-even f32 -> bf16 (manual RNE)
  union { float f; unsigned u; } v; v.f = f;
  return (u16)((v.u + 0x7FFFu + ((v.u >> 16) & 1u)) >> 16);
}
DEVI float bf2f(u16 h) {
  union { unsigned u; float f; } v; v.u = ((unsigned)h) << 16;
  return v.f;
}
DEVI void gload16(const void* g, void* l) {  // async global->LDS, 16B/lane
  __builtin_amdgcn_global_load_lds((const __attribute__((address_space(1))) void*)g,
                                   (__attribute__((address_space(3))) void*)l, 16, 0, 0);
}

// ------------------------------- converts ----------------------------------
__global__ __launch_bounds__(256) void k_cvt_all(
    const float* __restrict__ x,  const float* __restrict__ w0,
    const float* __restrict__ w1, const float* __restrict__ w2,
    const float* __restrict__ w3,
    u16* __restrict__ ox, u16* __restrict__ o0, u16* __restrict__ o1,
    u16* __restrict__ o2, u16* __restrict__ o3) {
  int blk = blockIdx.x;
  const float* in; u16* out; int i;
  if (blk < 16384) { in = x; out = ox; i = blk * 256 + threadIdx.x; }
  else {
    blk -= 16384;
    const int which = blk >> 12;       // 4096 blocks per weight
    in  = which == 0 ? w0 : which == 1 ? w1 : which == 2 ? w2 : w3;
    out = which == 0 ? o0 : which == 1 ? o1 : which == 2 ? o2 : o3;
    i = (blk & 4095) * 256 + threadIdx.x;
  }
  f4 v = ((const f4*)in)[i];
  us4 o;
  o[0] = f2bf(v[0]); o[1] = f2bf(v[1]); o[2] = f2bf(v[2]); o[3] = f2bf(v[3]);
  ((us4*)out)[i] = o;
}

// =================== 256x256 BK=64 8-phase GEMM core ========================
DEVI void stRA(const u16* __restrict__ Ag, int m0, u16* L, int q, int kt, int tid) {
  const int rl = tid >> 3, cc = tid & 7;
#pragma unroll
  for (int j = 0; j < 2; ++j) {
    const int row = j * 128 + q * 64 + rl;
    const int g = cc ^ (row & 7);
    gload16(Ag + (size_t)(m0 + row) * 2048 + kt * 64 + g * 8,
            (char*)L + ((size_t)row * 8 + cc) * 16);
  }
}
DEVI void stRB(const u16* __restrict__ Bg, int n0, u16* L, int q, int kt, int tid) {
  const int rl = tid >> 3, cc = tid & 7;
#pragma unroll
  for (int j = 0; j < 2; ++j) {
    const int row = (j * 2 + (rl >> 5)) * 64 + q * 32 + (rl & 31);
    const int g = cc ^ (row & 7);
    gload16(Bg + (size_t)(n0 + row) * 2048 + kt * 64 + g * 8,
            (char*)L + ((size_t)row * 8 + cc) * 16);
  }
}

DEVI void rdA4(sh8 (&af)[4][2], const u16* L, int mi0, int ln, int hi) {
#pragma unroll
  for (int m = 0; m < 4; ++m)
#pragma unroll
    for (int kk = 0; kk < 2; ++kk)
      af[m][kk] = *(const sh8*)&L[(size_t)((mi0 + m) * 16 + ln) * 64 +
                                  (((kk * 4 + hi) ^ (ln & 7)) * 8)];
}
DEVI void rdB2(sh8 (&bf)[2][2], const u16* L, int row0, int ln, int hi) {
#pragma unroll
  for (int n = 0; n < 2; ++n)
#pragma unroll
    for (int kk = 0; kk < 2; ++kk)
      bf[n][kk] = *(const sh8*)&L[(size_t)(row0 + n * 16 + ln) * 64 +
                                  (((kk * 4 + hi) ^ (ln & 7)) * 8)];
}

#define MFMA_BF16 __builtin_amdgcn_mfma_f32_16x16x32_bf16
#define MMQ(MB, NB, AF, BF)                                                  \
  _Pragma("unroll") for (int kk = 0; kk < 2; ++kk)                           \
  _Pragma("unroll") for (int m2 = 0; m2 < 4; ++m2)                           \
  _Pragma("unroll") for (int n2 = 0; n2 < 2; ++n2)                           \
    acc[MB + m2][NB + n2] =                                                  \
        MFMA_BF16(AF[m2][kk], BF[n2][kk], acc[MB + m2][NB + n2], 0, 0, 0);

#define PH_OPEN()                                              \
  __builtin_amdgcn_s_barrier();                                \
  asm volatile("s_waitcnt lgkmcnt(0)" ::: "memory");           \
  __builtin_amdgcn_sched_barrier(0);                           \
  __builtin_amdgcn_s_setprio(1)
#define PH_CLOSE()                                             \
  __builtin_amdgcn_s_setprio(0);                               \
  __builtin_amdgcn_s_barrier()

DEVI void g256_loop(const u16* __restrict__ Ag, const u16* __restrict__ Bg,
                    int m0, int n0,
                    u16 (&LA)[2][16384], u16 (&LB)[2][16384],
                    fx4 (&acc)[8][4]) {
  constexpr int NI = 16;
  const int tid = threadIdx.x;
  const int lane = tid & 63, ln = lane & 15, hi = lane >> 4;
  const int wid = tid >> 6, wr = wid >> 2, wc = wid & 3;
  const int hB = wc >> 1, rBb = (wc & 1) * 64;
  const u16* A0 = &LA[0][(size_t)wr * 128 * 64];
  const u16* A1 = &LA[1][(size_t)wr * 128 * 64];
  const int rB0 = hB * 128 + rBb;

  stRA(Ag, m0, &LA[0][0], 0, 0, tid);
  stRB(Bg, n0, &LB[0][0], 0, 0, tid);
  stRA(Ag, m0, &LA[0][0], 1, 0, tid);
  stRB(Bg, n0, &LB[0][0], 1, 0, tid);
  stRA(Ag, m0, &LA[1][0], 0, 1, tid);
  stRB(Bg, n0, &LB[1][0], 0, 1, tid);
  asm volatile("s_waitcnt vmcnt(4)" ::: "memory");
  __builtin_amdgcn_s_barrier();

  sh8 af[4][2], bflo[2][2], bfhi[2][2];

  for (int i = 0; i < NI; ++i) {
    const int ta = 2 * i, tb = 2 * i + 1;
    const bool stg = (i + 1 < NI);

    rdA4(af, A0, 0, ln, hi);
    rdB2(bflo, &LB[0][0], rB0, ln, hi);
    stRA(Ag, m0, &LA[1][0], 1, tb, tid);
    PH_OPEN(); MMQ(0, 0, af, bflo); PH_CLOSE();

    rdB2(bfhi, &LB[0][0], rB0 + 32, ln, hi);
    stRB(Bg, n0, &LB[1][0], 1, tb, tid);
    PH_OPEN(); MMQ(0, 2, af, bfhi); PH_CLOSE();

    rdA4(af, A0, 4, ln, hi);
    if (stg) stRA(Ag, m0, &LA[0][0], 0, ta + 2, tid);
    PH_OPEN(); MMQ(4, 0, af, bflo); PH_CLOSE();

    if (stg) stRB(Bg, n0, &LB[0][0], 0, ta + 2, tid);
    PH_OPEN(); MMQ(4, 2, af, bfhi);
    __builtin_amdgcn_s_setprio(0);
    if (i + 1 < NI) asm volatile("s_waitcnt vmcnt(4)" ::: "memory");
    else            asm volatile("s_waitcnt vmcnt(0)" ::: "memory");
    __builtin_amdgcn_s_barrier();

    rdA4(af, A1, 0, ln, hi);
    rdB2(bflo, &LB[1][0], rB0, ln, hi);
    if (stg) stRB(Bg, n0, &LB[0][0], 1, ta + 2, tid);
    PH_OPEN(); MMQ(0, 0, af, bflo); PH_CLOSE();

    rdB2(bfhi, &LB[1][0], rB0 + 32, ln, hi);
    if (stg) stRA(Ag, m0, &LA[0][0], 1, ta + 2, tid);
    PH_OPEN(); MMQ(0, 2, af, bfhi); PH_CLOSE();

    rdA4(af, A1, 4, ln, hi);
    if (stg) stRA(Ag, m0, &LA[1][0], 0, tb + 2, tid);
    PH_OPEN(); MMQ(4, 0, af, bflo); PH_CLOSE();

    if (stg) stRB(Bg, n0, &LB[1][0], 0, tb + 2, tid);
    PH_OPEN(); MMQ(4, 2, af, bfhi);
    __builtin_amdgcn_s_setprio(0);
    asm volatile("s_waitcnt vmcnt(4)" ::: "memory");
    __builtin_amdgcn_s_barrier();
  }
}

// QKV projection with fused epilogue:
//  z=0: +bias, per-head RMSNorm * qnw * log2e/sqrt(128) -> Q [B,H,T,Hd]
//  z=1: +bias, per-head RMSNorm * knw                   -> K [B,H,T,Hd]
//  z=2: +bias                                           -> V^T [B,H,Hd,T]
__global__ __launch_bounds__(512, 2) void k_gemm_qkv(
    const u16* __restrict__ A,
    const u16* __restrict__ W0, const u16* __restrict__ W1, const u16* __restrict__ W2,
    const float* __restrict__ b0, const float* __restrict__ b1, const float* __restrict__ b2,
    const float* __restrict__ qn, const float* __restrict__ kn,
    u16* __restrict__ O0, u16* __restrict__ O1, u16* __restrict__ O2) {
  __shared__ __align__(16) u16 LA[2][16384];
  __shared__ __align__(16) u16 LB[2][16384];
  int f = blockIdx.x + (blockIdx.y << 3) + (blockIdx.z << 8);
  f = (f & 7) * 96 + (f >> 3);
  const int z = f >> 8, rem = f & 255;
  const int m0 = (rem >> 3) * 256, n0 = (rem & 7) * 256;
  const u16* Bw = z == 0 ? W0 : z == 1 ? W1 : W2;
  const float* bias = z == 0 ? b0 : z == 1 ? b1 : b2;
  u16* Cout = z == 0 ? O0 : z == 1 ? O1 : O2;

  fx4 acc[8][4] = {};
  g256_loop(A, Bw, m0, n0, LA, LB, acc);

  const int tid = threadIdx.x;
  const int lane = tid & 63, ln = lane & 15, hi = lane >> 4;
  const int wid = tid >> 6, wr = wid >> 2, wc = wid & 3;

#pragma unroll
  for (int nj = 0; nj < 4; ++nj) {
    const float bv = bias[n0 + wc * 64 + nj * 16 + ln];
#pragma unroll
    for (int mi = 0; mi < 8; ++mi)
#pragma unroll
      for (int j = 0; j < 4; ++j) acc[mi][nj][j] += bv;
  }

  if (z < 2) {
    float ss[8][4];
#pragma unroll
    for (int mi = 0; mi < 8; ++mi)
#pragma unroll
      for (int j = 0; j < 4; ++j) {
        float s = 0.0f;
#pragma unroll
        for (int nj = 0; nj < 4; ++nj) s += acc[mi][nj][j] * acc[mi][nj][j];
#pragma unroll
        for (int m = 1; m < 16; m <<= 1) s += __shfl_xor(s, m);
        ss[mi][j] = s;
      }
    float* sums = (float*)&LA[0][0];  // 4 KB scratch, LDS dead post-loop
    __syncthreads();
    if (ln == 0) {
#pragma unroll
      for (int mi = 0; mi < 8; ++mi)
#pragma unroll
        for (int j = 0; j < 4; ++j)
          sums[(wr * 4 + wc) * 128 + mi * 16 + hi * 4 + j] = ss[mi][j];
    }
    __syncthreads();
    const float zscale = z == 0 ? 0.12751745047f : 1.0f;  // log2e/sqrt(128)
    const float* wnorm = z == 0 ? qn : kn;
#pragma unroll
    for (int mi = 0; mi < 8; ++mi)
#pragma unroll
      for (int j = 0; j < 4; ++j) {
        const float tot = ss[mi][j] +
            sums[(wr * 4 + (wc ^ 1)) * 128 + mi * 16 + hi * 4 + j];
        ss[mi][j] = rsqrtf(tot * (1.0f / 128.0f) + 1.1920928955078125e-07f) * zscale;
      }
#pragma unroll
    for (int mi = 0; mi < 8; ++mi) {
#pragma unroll
      for (int nj = 0; nj < 4; ++nj) {
        const int col = n0 + wc * 64 + nj * 16 + ln;
        const int h = col >> 7, d = col & 127;
        const float wv = wnorm[d];
#pragma unroll
        for (int j = 0; j < 4; ++j) {
          const int row = m0 + wr * 128 + mi * 16 + hi * 4 + j;
          const int b = row >> 11, t = row & 2047;
          Cout[((((size_t)b * 16 + h) * 2048) + t) * 128 + d] =
              f2bf(acc[mi][nj][j] * ss[mi][j] * wv);
        }
      }
    }
  } else {
#pragma unroll
    for (int mi = 0; mi < 8; ++mi) {
#pragma unroll
      for (int nj = 0; nj < 4; ++nj) {
        const int col = n0 + wc * 64 + nj * 16 + ln;
        const int h = col >> 7, d = col & 127;
        const int row0 = m0 + wr * 128 + mi * 16 + hi * 4;
        const int b = row0 >> 11, t = row0 & 2047;
        us4 v;
#pragma unroll
        for (int j = 0; j < 4; ++j) v[j] = f2bf(acc[mi][nj][j]);
        *(us4*)&Cout[((((size_t)b * 16 + h) * 128) + d) * 2048 + t] = v;
      }
    }
  }
}

// Output projection: fp32 row-major + bias.
__global__ __launch_bounds__(512, 2) void k_gemm_out(const u16* __restrict__ A,
                                                     const u16* __restrict__ Bw,
                                                     const float* __restrict__ bias,
                                                     float* __restrict__ C) {
  __shared__ __align__(16) u16 LA[2][16384];
  __shared__ __align__(16) u16 LB[2][16384];
  int f = blockIdx.x + (blockIdx.y << 3);
  f = (f & 7) * 32 + (f >> 3);
  const int m0 = (f >> 3) * 256, n0 = (f & 7) * 256;

  fx4 acc[8][4] = {};
  g256_loop(A, Bw, m0, n0, LA, LB, acc);

  const int tid = threadIdx.x;
  const int lane = tid & 63, ln = lane & 15, hi = lane >> 4;
  const int wid = tid >> 6, wr = wid >> 2, wc = wid & 3;
#pragma unroll
  for (int mi = 0; mi < 8; ++mi) {
#pragma unroll
    for (int nj = 0; nj < 4; ++nj) {
      const int col = n0 + wc * 64 + nj * 16 + ln;
      const float bv = bias[col];
#pragma unroll
      for (int j = 0; j < 4; ++j) {
        const int row = m0 + wr * 128 + mi * 16 + hi * 4 + j;
        C[(size_t)row * 2048 + col] = acc[mi][nj][j] + bv;
      }
    }
  }
}

// --------------------------- Flash attention -------------------------------
// 4 waves x 32 q-rows, KV tile 64.  Swapped QK^T (S^T = K.Q^T), packed 8B
// P-writes, fixed-max base-2 softmax (log2e folded into Q), 2-phase dbuf.
// R17: bijective XCD-affinity remap -- all 16 q-blocks of a bh on one XCD
// (K/V L2-resident -> staging latency L2-class, hidden by the pipeline).
__global__ __launch_bounds__(256, 2) void k_attn(const u16* __restrict__ Q,
                                                 const u16* __restrict__ Kt,
                                                 const u16* __restrict__ Vt,
                                                 u16* __restrict__ Aout) {
  constexpr int T = 2048, Hd = 128;
  __shared__ __align__(16) u16 Ks[2][64 * 128];
  __shared__ __align__(16) u16 Vs[2][128 * 64];
  __shared__ __align__(16) u16 Ps[4 * 32 * 64];
  const int tid = threadIdx.x;
  const int w = tid >> 6, lane = tid & 63;
  const int ln = lane & 15, hi = lane >> 4;
  // XCD-affinity remap over 1024 blocks: xcd = L&7 gets bh in [xcd*8, xcd*8+8)
  const int L = blockIdx.x + (blockIdx.y << 4);
  const int jj = L >> 3;
  const int bh = (L & 7) * 8 + (jj >> 4);
  const int q0 = (jj & 15) * 128 + w * 32;

  const u16* Kgb = Kt + (size_t)bh * T * Hd;
  const u16* Vgb = Vt + (size_t)bh * Hd * T;
  u16* Pw = Ps + w * 2048;

  sh8 qf[2][4];
  const u16* Qb = Q + ((size_t)bh * T + q0) * Hd;
#pragma unroll
  for (int mi = 0; mi < 2; ++mi)
#pragma unroll
    for (int ks = 0; ks < 4; ++ks)
      qf[mi][ks] = *(const sh8*)(Qb + (size_t)(mi * 16 + ln) * Hd + ks * 32 + hi * 8);

  fx4 o[2][8] = {};
  float lsum[2] = {0.0f, 0.0f};

  auto stage = [&](int buf, int t0) {
#pragma unroll
    for (int i = 0; i < 4; ++i) {
      const int c = i * 256 + tid;
      const int r = c >> 4, cc = (c & 15) ^ (r & 7);
      gload16(Kgb + (size_t)(t0 + r) * Hd + cc * 8, (char*)&Ks[buf][0] + c * 16);
    }
#pragma unroll
    for (int i = 0; i < 4; ++i) {
      const int c = i * 256 + tid;
      const int r = c >> 3, cc = (c & 7) ^ (r & 7);
      gload16(Vgb + (size_t)r * T + t0 + cc * 8, (char*)&Vs[buf][0] + c * 16);
    }
  };

  stage(0, 0);
  __syncthreads();
  int cur = 0;

  for (int t0 = 0; t0 < T; t0 += 64) {
    if (t0 + 64 < T) stage(cur ^ 1, t0 + 64);

#pragma unroll
    for (int ni = 0; ni < 4; ++ni) {
      sh8 kf[4];
#pragma unroll
      for (int ks = 0; ks < 4; ++ks)
        kf[ks] = *(const sh8*)&Ks[cur][(((ni * 16 + ln) * 128) + ks * 32 + hi * 8) ^ ((ln & 7) << 3)];
      fx4 st[2] = {};
#pragma unroll
      for (int mi = 0; mi < 2; ++mi)
#pragma unroll
        for (int ks = 0; ks < 4; ++ks)
          st[mi] = MFMA_BF16(kf[ks], qf[mi][ks], st[mi], 0, 0, 0);
#pragma unroll
      for (int mi = 0; mi < 2; ++mi) {
        const float p0 = __builtin_amdgcn_exp2f(st[mi][0] - 17.31234049066756f);
        const float p1 = __builtin_amdgcn_exp2f(st[mi][1] - 17.31234049066756f);
        const float p2 = __builtin_amdgcn_exp2f(st[mi][2] - 17.31234049066756f);
        const float p3 = __builtin_amdgcn_exp2f(st[mi][3] - 17.31234049066756f);
        lsum[mi] += (p0 + p1) + (p2 + p3);
        const unsigned lo = (unsigned)f2bf(p0) | ((unsigned)f2bf(p1) << 16);
        const unsigned hw = (unsigned)f2bf(p2) | ((unsigned)f2bf(p3) << 16);
        const int idx = (((mi * 16 + ln) * 64) + ni * 16 + hi * 4) ^ ((ln & 7) << 3);
        *(uix2*)&Pw[idx] = (uix2){lo, hw};
      }
    }

#pragma unroll
    for (int ks = 0; ks < 2; ++ks) {
      sh8 pf[2];
#pragma unroll
      for (int mi = 0; mi < 2; ++mi)
        pf[mi] = *(const sh8*)&Pw[(((mi * 16 + ln) * 64) + ks * 32 + hi * 8) ^ ((ln & 7) << 3)];
#pragma unroll
      for (int di = 0; di < 8; ++di) {
        const sh8 vf = *(const sh8*)&Vs[cur][(((di * 16 + ln) * 64) + ks * 32 + hi * 8) ^ ((ln & 7) << 3)];
#pragma unroll
        for (int mi = 0; mi < 2; ++mi)
          o[mi][di] = MFMA_BF16(pf[mi], vf, o[mi][di], 0, 0, 0);
      }
    }

    __syncthreads();
    cur ^= 1;
  }

#pragma unroll
  for (int mi = 0; mi < 2; ++mi) {
    lsum[mi] += __shfl_xor(lsum[mi], 16);
    lsum[mi] += __shfl_xor(lsum[mi], 32);
  }

  const int b = bh >> 4, h = bh & 15;
  u16* Ob = Aout + ((size_t)b * T + q0) * 2048 + h * 128;
#pragma unroll
  for (int mi = 0; mi < 2; ++mi) {
    fx4 rv;
#pragma unroll
    for (int j = 0; j < 4; ++j)
      rv[j] = 1.0f / __shfl(lsum[mi], 20 * (lane >> 4) + j);
#pragma unroll
    for (int di = 0; di < 8; ++di) {
      fx4 val = o[mi][di] * rv;
#pragma unroll
      for (int j = 0; j < 4; ++j)
        Ob[(size_t)(mi * 16 + hi * 4 + j) * 2048 + di * 16 + ln] = f2bf(val[j]);
    }
  }
}

// ---------------------------------------------------------------------------
extern "C" void kernel_launch(void* const* d_in, const int* in_sizes, int n_in,
                              void* d_out, int out_size, void* d_ws, size_t ws_size,
                              hipStream_t stream) {
  const float* x   = (const float*)d_in[0];
  const float* Wq  = (const float*)d_in[1];
  const float* bq  = (const float*)d_in[2];
  const float* Wk  = (const float*)d_in[3];
  const float* bk  = (const float*)d_in[4];
  const float* Wv  = (const float*)d_in[5];
  const float* bv  = (const float*)d_in[6];
  const float* qnw = (const float*)d_in[7];
  const float* knw = (const float*)d_in[8];
  const float* Wo  = (const float*)d_in[9];
  const float* bo  = (const float*)d_in[10];
  float* out = (float*)d_out;

  const size_t SZ_X = 33554432;  // 8192*2048 bf16
  const size_t SZ_W = 8388608;   // 2048*2048 bf16
  char* ws = (char*)d_ws;
  u16* xb  = (u16*)(ws);
  u16* Wqb = (u16*)(ws + SZ_X);
  u16* Wkb = (u16*)(ws + SZ_X + SZ_W);
  u16* Wvb = (u16*)(ws + SZ_X + 2 * SZ_W);
  u16* Wob = (u16*)(ws + SZ_X + 3 * SZ_W);
  u16* Qb  = (u16*)(ws + SZ_X + 4 * SZ_W);
  u16* Kb  = (u16*)(ws + 2 * SZ_X + 4 * SZ_W);
  u16* Vb  = (u16*)(ws + 3 * SZ_X + 4 * SZ_W);   // attn-out scratch
  u16* Vtb = (u16*)(ws + 4 * SZ_X + 4 * SZ_W);
  u16* AOb = Vb;

  k_cvt_all<<<32768, 256, 0, stream>>>(x, Wq, Wk, Wv, Wo, xb, Wqb, Wkb, Wvb, Wob);
  k_gemm_qkv<<<dim3(8, 32, 3), 512, 0, stream>>>(xb, Wqb, Wkb, Wvb, bq, bk, bv,
                                                 qnw, knw, Qb, Kb, Vtb);
  k_attn<<<dim3(16, 64), 256, 0, stream>>>(Qb, Kb, Vtb, AOb);
  k_gemm_out<<<dim3(8, 32), 512, 0, stream>>>(AOb, Wob, bo, out);
}